// Round 1
// 1366.570 us; speedup vs baseline: 8.3008x; 8.3008x over previous
//
#include <hip/hip_runtime.h>

// Problem constants: B=4, T=2048, D=1024, H=16, HD=64
// Math (certified r6): torch convention x@W.T+b, rotate-half RoPE pos=t+1,
// causal softmax(QK^T/8)V, O-proj. Output f32 [B,T,D].
#define BB 4
#define TT 2048
#define DD 1024
#define HH 16
#define HD 64

typedef __attribute__((ext_vector_type(8))) __bf16 bf16x8;
typedef __attribute__((ext_vector_type(4))) float f32x4;
typedef __attribute__((ext_vector_type(2))) unsigned int u32x2;
typedef __attribute__((ext_vector_type(4))) unsigned int u32x4;

__device__ __forceinline__ float b2f(unsigned short u) {
    return __uint_as_float(((unsigned int)u) << 16);
}
__device__ __forceinline__ unsigned short f2b(float f) {
    unsigned int i = __float_as_uint(f);
    unsigned int r = i + 0x7fffu + ((i >> 16) & 1u);   // round-to-nearest-even
    return (unsigned short)(r >> 16);
}

// ---------------------------------------------------------------------------
// Tiled GEMM (torch convention): out[n,j] = sum_k A[n,k] * W[j,k] + bias[j]
// mode==1: bf16 scatter out[((b*H+h)*T+t)*64+dd]   (q/k/v staging)
// mode==0: f32 flat   out[n*J + j]                  (final output)
// ---------------------------------------------------------------------------
__global__ __launch_bounds__(256) void gemm_f32(
    const float* __restrict__ A, const float* __restrict__ W,
    const float* __restrict__ bias, void* __restrict__ outp,
    int N, int K, int J, int mode)
{
    __shared__ float As[32][68];
    __shared__ float Ws[32][68];

    const int tid = threadIdx.x;
    const int tx = tid & 15, ty = tid >> 4;
    const int n0 = blockIdx.y * 64;
    const int j0 = blockIdx.x * 64;
    const int tx4 = tx * 4, ty4 = ty * 4;

    float acc[4][4] = {};

    for (int k0 = 0; k0 < K; k0 += 32) {
        __syncthreads();
#pragma unroll
        for (int vv = 0; vv < 2; vv++) {
            int vi = tid + vv * 256;       // 0..511
            int r = vi >> 3;               // row 0..63
            int c = (vi & 7) << 2;         // k-offset 0..28
            float4 av = *(const float4*)(A + (size_t)(n0 + r) * K + (k0 + c));
            As[c + 0][r] = av.x; As[c + 1][r] = av.y;
            As[c + 2][r] = av.z; As[c + 3][r] = av.w;
            float4 wv = *(const float4*)(W + (size_t)(j0 + r) * K + (k0 + c));
            Ws[c + 0][r] = wv.x; Ws[c + 1][r] = wv.y;
            Ws[c + 2][r] = wv.z; Ws[c + 3][r] = wv.w;
        }
        __syncthreads();
#pragma unroll
        for (int kk = 0; kk < 32; kk++) {
            float4 av = *(const float4*)&As[kk][ty4];
            float4 wv = *(const float4*)&Ws[kk][tx4];
            acc[0][0] += av.x * wv.x; acc[0][1] += av.x * wv.y;
            acc[0][2] += av.x * wv.z; acc[0][3] += av.x * wv.w;
            acc[1][0] += av.y * wv.x; acc[1][1] += av.y * wv.y;
            acc[1][2] += av.y * wv.z; acc[1][3] += av.y * wv.w;
            acc[2][0] += av.z * wv.x; acc[2][1] += av.z * wv.y;
            acc[2][2] += av.z * wv.z; acc[2][3] += av.z * wv.w;
            acc[3][0] += av.w * wv.x; acc[3][1] += av.w * wv.y;
            acc[3][2] += av.w * wv.z; acc[3][3] += av.w * wv.w;
        }
    }

    float bb4[4];
#pragma unroll
    for (int jj = 0; jj < 4; jj++) bb4[jj] = bias[j0 + tx4 + jj];

#pragma unroll
    for (int i = 0; i < 4; i++) {
        int n = n0 + ty4 + i;
#pragma unroll
        for (int jj = 0; jj < 4; jj++) {
            int j = j0 + tx4 + jj;
            float v = acc[i][jj] + bb4[jj];
            if (mode == 0) {
                ((float*)outp)[(size_t)n * J + j] = v;
            } else {
                int b = n >> 11, t = n & (TT - 1);
                int h = j >> 6, dd = j & 63;
                ((unsigned short*)outp)[(((size_t)(b * HH + h) * TT + t) << 6) + dd] = f2b(v);
            }
        }
    }
}

// ---------------------------------------------------------------------------
// RoPE (rotate-half) in-place on [B,H,T,64] bf16.
// ---------------------------------------------------------------------------
__global__ __launch_bounds__(256) void rope_kernel(unsigned short* __restrict__ buf)
{
    int idx = blockIdx.x * 256 + threadIdx.x;    // B*H*T*32 total
    int i = idx & 31;
    int t = (idx >> 5) & (TT - 1);
    int bh = idx >> 16;
    size_t base = ((size_t)bh * TT + t) * 64;
    float x1 = b2f(buf[base + i]);
    float x2 = b2f(buf[base + 32 + i]);
    float theta = exp2f(-(float)i * (13.287712379549449f / 32.0f));
    float ang = (float)(t + 1) * theta;
    float s = sinf(ang), c = cosf(ang);
    buf[base + i]       = f2b(x1 * c - x2 * s);
    buf[base + 32 + i]  = f2b(x2 * c + x1 * s);
}

// ---------------------------------------------------------------------------
// MFMA flash attention.
// Grid: (T/64, H, B); block 256 = 4 waves; wave w owns q-rows q0+w*16..+15.
// Per KV tile (64 keys): stage K (XOR-swizzled rows) + V ([db][key][16]
// subtiles) in LDS; S^T = K*Q^T via mfma_16x16x32_bf16 (C/D rows = keys,
// cols = q-rows -> softmax is per-lane over 16 regs + 2 shfl_xor); P stays
// in registers (C/D row layout == A-fragment k layout); V fragments via
// ds_read_b64_tr_b16 from the subtiled layout. f32 online-softmax state.
// ---------------------------------------------------------------------------
__device__ __forceinline__ u32x2 ds_tr16(const unsigned short* p) {
    u32x2 r;
    asm volatile("ds_read_b64_tr_b16 %0, %1"
                 : "=v"(r)
                 : "v"((unsigned int)(unsigned long long)p));
    return r;
}

__global__ __launch_bounds__(256) void attn_mfma(
    const unsigned short* __restrict__ q,
    const unsigned short* __restrict__ k,
    const unsigned short* __restrict__ v,
    float* __restrict__ aout)
{
    __shared__ __align__(16) unsigned short Ks[64 * 64];   // swizzled [key][dim]
    __shared__ __align__(16) unsigned short Vs[4 * 1056];  // [db][key][16], db stride padded

    const int qt = blockIdx.x, h = blockIdx.y, b = blockIdx.z;
    const int tid = threadIdx.x;
    const int w = tid >> 6;          // wave 0..3
    const int lane = tid & 63;
    const int l15 = lane & 15, g = lane >> 4;
    const int bh = b * HH + h;
    const size_t base = (size_t)bh * TT * 64;
    const unsigned short* Qp = q + base;
    const unsigned short* Kp = k + base;
    const unsigned short* Vp = v + base;
    const int q0 = qt * 64;

    // Q fragments (held for whole block). A/B frag layout: lane holds
    // row (l&15), k = 4*(lane>>4) + (j&3) + 16*(j>>2) (+32 per chunk c).
    bf16x8 qf[2];
    {
        const unsigned short* Qr = Qp + (size_t)(q0 + w * 16 + l15) * 64;
#pragma unroll
        for (int c = 0; c < 2; c++) {
            u32x2 a0 = *(const u32x2*)(Qr + 32 * c + 4 * g);
            u32x2 a1 = *(const u32x2*)(Qr + 32 * c + 16 + 4 * g);
            u32x4 uu = {a0.x, a0.y, a1.x, a1.y};
            qf[c] = __builtin_bit_cast(bf16x8, uu);
        }
    }

    float mrow = -1e30f, lrow = 0.f;
    f32x4 accO[4];
#pragma unroll
    for (int nb = 0; nb < 4; nb++) accO[nb] = (f32x4){0.f, 0.f, 0.f, 0.f};

    const float SC = 0.18033688011112042f;   // log2(e) / 8  (softmax scale folded in)

    const int ntiles = qt + 1;
    for (int kt = 0; kt < ntiles; kt++) {
        const int kbase = kt * 64;
        const bool diag = (kt == qt);
        __syncthreads();
        // ---- stage K: 512 x 16B chunks, rows XOR-swizzled at 16B granularity
#pragma unroll
        for (int it = 0; it < 2; it++) {
            int vi = tid + it * 256;
            int key = vi >> 3, pr = vi & 7;
            u32x4 val = *(const u32x4*)(Kp + (size_t)(kbase + key) * 64 + pr * 8);
            *(u32x4*)(Ks + key * 64 + ((pr ^ (key & 7)) << 3)) = val;
        }
        // ---- stage V: 1024 x 8B chunks into [db][key][16] subtiles
#pragma unroll
        for (int it = 0; it < 4; it++) {
            int vi = tid + it * 256;
            int key = vi >> 4, c4 = vi & 15;
            u32x2 val = *(const u32x2*)(Vp + (size_t)(kbase + key) * 64 + c4 * 4);
            *(u32x2*)(Vs + (c4 >> 2) * 1056 + key * 16 + (c4 & 3) * 4) = val;
        }
        __syncthreads();

        // ---- S^T = K * Q^T : accS[kb] reg r <-> key kb*16+4g+r, col q-row l15
        const int nkb = diag ? (w + 1) : 4;
        f32x4 accS[4];
#pragma unroll
        for (int kb = 0; kb < 4; kb++) accS[kb] = (f32x4){0.f, 0.f, 0.f, 0.f};
#pragma unroll
        for (int kb = 0; kb < 4; kb++) {
            if (kb < nkb) {
                int key = kb * 16 + l15;
                int sw = key & 7;
#pragma unroll
                for (int c = 0; c < 2; c++) {
                    int c8a = 8 * c + g, c8b = 8 * c + 4 + g;
                    u32x2 x0 = *(const u32x2*)(Ks + key * 64 +
                                   (((c8a >> 1) ^ sw) << 3) + ((c8a & 1) << 2));
                    u32x2 x1 = *(const u32x2*)(Ks + key * 64 +
                                   (((c8b >> 1) ^ sw) << 3) + ((c8b & 1) << 2));
                    u32x4 uu = {x0.x, x0.y, x1.x, x1.y};
                    accS[kb] = __builtin_amdgcn_mfma_f32_16x16x32_bf16(
                        __builtin_bit_cast(bf16x8, uu), qf[c], accS[kb], 0, 0, 0);
                }
            }
        }

        // ---- mask (diag) + per-row max (lane holds 16 keys of q-row l15)
        float sloc[16];
        float tmax = -1e30f;
#pragma unroll
        for (int kb = 0; kb < 4; kb++)
#pragma unroll
            for (int r = 0; r < 4; r++) {
                float s = accS[kb][r];
                bool valid = !diag || (kb * 16 + 4 * g + r <= w * 16 + l15);
                s = valid ? s : -1e30f;
                sloc[kb * 4 + r] = s;
                tmax = fmaxf(tmax, s);
            }
        tmax = fmaxf(tmax, __shfl_xor(tmax, 16));
        tmax = fmaxf(tmax, __shfl_xor(tmax, 32));

        float mnew = fmaxf(mrow, tmax);
        float sf = exp2f((mrow - mnew) * SC);
        mrow = mnew;

        // ---- P = exp, rounded to bf16; l accumulates the ROUNDED p
        unsigned int pw[8];
        float psum = 0.f;
#pragma unroll
        for (int i = 0; i < 8; i++) {
            float p0 = exp2f((sloc[2 * i]     - mnew) * SC);
            float p1 = exp2f((sloc[2 * i + 1] - mnew) * SC);
            unsigned short h0 = f2b(p0), h1 = f2b(p1);
            pw[i] = (unsigned int)h0 | ((unsigned int)h1 << 16);
            psum += b2f(h0) + b2f(h1);
        }
        psum += __shfl_xor(psum, 16);
        psum += __shfl_xor(psum, 32);
        lrow = lrow * sf + psum;

        // ---- rescale O (its rows are q-rows 4g+r -> fetch sf from lane 4g+r)
        float sfr[4];
#pragma unroll
        for (int r = 0; r < 4; r++) sfr[r] = __shfl(sf, 4 * g + r);
#pragma unroll
        for (int nb = 0; nb < 4; nb++)
#pragma unroll
            for (int r = 0; r < 4; r++) accO[nb][r] *= sfr[r];

        // ---- V fragments via hardware transpose read, then PV MFMAs.
        // P fragment comes straight from pw (C/D row layout == A k-layout).
        const int nkc = (diag && w < 2) ? 1 : 2;
        u32x2 vfr[2][4][2];
#pragma unroll
        for (int kc = 0; kc < 2; kc++)
            if (kc < nkc)
#pragma unroll
                for (int nb = 0; nb < 4; nb++)
#pragma unroll
                    for (int t2 = 0; t2 < 2; t2++)
                        vfr[kc][nb][t2] = ds_tr16(
                            Vs + nb * 1056 + (kc * 32 + 16 * t2) * 16 + 4 * lane);
        asm volatile("s_waitcnt lgkmcnt(0)" ::: "memory");
        __builtin_amdgcn_sched_barrier(0);

#pragma unroll
        for (int kc = 0; kc < 2; kc++)
            if (kc < nkc) {
                u32x4 pu = {pw[4 * kc + 0], pw[4 * kc + 1], pw[4 * kc + 2], pw[4 * kc + 3]};
                bf16x8 pf = __builtin_bit_cast(bf16x8, pu);
#pragma unroll
                for (int nb = 0; nb < 4; nb++) {
                    u32x4 vu = {vfr[kc][nb][0].x, vfr[kc][nb][0].y,
                                vfr[kc][nb][1].x, vfr[kc][nb][1].y};
                    accO[nb] = __builtin_amdgcn_mfma_f32_16x16x32_bf16(
                        pf, __builtin_bit_cast(bf16x8, vu), accO[nb], 0, 0, 0);
                }
            }
    }

    // ---- epilogue: O /= l ; write f32 [B,T,D]
    float linv = 1.0f / lrow;
    float sfr[4];
#pragma unroll
    for (int r = 0; r < 4; r++) sfr[r] = __shfl(linv, 4 * g + r);
#pragma unroll
    for (int r = 0; r < 4; r++) {
        int qr = q0 + w * 16 + 4 * g + r;
        float* orow = aout + (size_t)(b * TT + qr) * DD + h * 64;
#pragma unroll
        for (int nb = 0; nb < 4; nb++)
            orow[nb * 16 + l15] = accO[nb][r] * sfr[r];
    }
}

// ---------------------------------------------------------------------------
extern "C" void kernel_launch(void* const* d_in, const int* in_sizes, int n_in,
                              void* d_out, int out_size, void* d_ws, size_t ws_size,
                              hipStream_t stream)
{
    const float* x  = (const float*)d_in[0];
    const float* Wq = (const float*)d_in[1];
    const float* bq = (const float*)d_in[2];
    const float* Wk = (const float*)d_in[3];
    const float* bk = (const float*)d_in[4];
    const float* Wv = (const float*)d_in[5];
    const float* bv = (const float*)d_in[6];
    const float* Wo = (const float*)d_in[7];
    const float* bo = (const float*)d_in[8];
    float* out = (float*)d_out;                     // FLOAT32 output [B,T,D]

    const size_t NE = (size_t)BB * HH * TT * HD;    // 8388608 elements
    unsigned short* q    = (unsigned short*)d_ws;
    unsigned short* kbuf = q + NE;
    unsigned short* vbuf = kbuf + NE;
    float* res = (float*)d_ws;                      // overlays dead q+k after attn

    const int N = BB * TT;                          // 8192 tokens
    dim3 blk(256);
    dim3 gp(DD / 64, N / 64);                       // (16, 128)

    gemm_f32<<<gp, blk, 0, stream>>>(x, Wq, bq, q,    N, DD, DD, 1);
    gemm_f32<<<gp, blk, 0, stream>>>(x, Wk, bk, kbuf, N, DD, DD, 1);
    gemm_f32<<<gp, blk, 0, stream>>>(x, Wv, bv, vbuf, N, DD, DD, 1);

    int rope_total = BB * HH * TT * 32;             // 4194304
    rope_kernel<<<rope_total / 256, 256, 0, stream>>>(q);
    rope_kernel<<<rope_total / 256, 256, 0, stream>>>(kbuf);

    // MFMA flash attention -> f32 [B,T,D] straight into d_out
    attn_mfma<<<dim3(TT / 64, HH, BB), blk, 0, stream>>>(q, kbuf, vbuf, out);

    // O-projection: A = d_out (f32), result f32 -> res (dead q+k region)
    gemm_f32<<<gp, blk, 0, stream>>>(out, Wo, bo, res, N, DD, DD, 0);

    // copy result back to d_out
    hipMemcpyAsync(out, res, (size_t)N * DD * sizeof(float),
                   hipMemcpyDeviceToDevice, stream);
}

// Round 2
// 493.696 us; speedup vs baseline: 22.9769x; 2.7680x over previous
//
#include <hip/hip_runtime.h>

// Problem constants: B=4, T=2048, D=1024, H=16, HD=64
// Math (certified r6): torch convention x@W.T+b, rotate-half RoPE pos=t+1,
// causal softmax(QK^T/8)V, O-proj. Output f32 [B,T,D].
// R2: full-FP16 pipeline. x,W converted to f16 (d_out used as scratch);
// q/k/v/attn-out f16; all 4 projections via 16x16x32 f16 MFMA GEMM.
#define BB 4
#define TT 2048
#define DD 1024
#define HH 16
#define HD 64

typedef __attribute__((ext_vector_type(8))) _Float16 f16x8;
typedef __attribute__((ext_vector_type(4))) float f32x4;
typedef __attribute__((ext_vector_type(2))) unsigned int u32x2;
typedef __attribute__((ext_vector_type(4))) unsigned int u32x4;

__device__ __forceinline__ float h2f(unsigned short u) {
    return (float)__builtin_bit_cast(_Float16, u);
}
__device__ __forceinline__ unsigned short f2h(float f) {
    return __builtin_bit_cast(unsigned short, (_Float16)f);
}

// ---------------------------------------------------------------------------
// f32 -> f16 convert (vectorized, exact grid)
// ---------------------------------------------------------------------------
__global__ __launch_bounds__(256) void conv_h(
    const float* __restrict__ in, unsigned short* __restrict__ out, int n4)
{
    int i = blockIdx.x * 256 + threadIdx.x;
    if (i < n4) {
        float4 v = ((const float4*)in)[i];
        ushort4 o = { f2h(v.x), f2h(v.y), f2h(v.z), f2h(v.w) };
        ((ushort4*)out)[i] = o;
    }
}

// ---------------------------------------------------------------------------
// MFMA f16 GEMM (torch convention): out[n,j] = sum_k A[n,k]*W[j,k] + bias[j]
// A: [N,K] f16 row-major; W: [J,K] f16 row-major (both k-contiguous).
// Block 256 = 4 waves (2x2), tile 128x128, BK=64; per-wave 64x64 = 4x4 frags
// of 16x16x32. LDS tiles XOR-swizzled at 16B granularity (chunk ^= row&7).
// Reg-staged with next-tile prefetch. mode 1: f16 scatter [B,H,T,64];
// mode 0: f32 flat [n*J+j].
// ---------------------------------------------------------------------------
__global__ __launch_bounds__(256) void gemm_h(
    const unsigned short* __restrict__ A, const unsigned short* __restrict__ W,
    const float* __restrict__ bias, void* __restrict__ outp,
    int N, int K, int J, int mode)
{
    __shared__ __align__(16) unsigned short As[128 * 64];
    __shared__ __align__(16) unsigned short Ws[128 * 64];

    const int tid = threadIdx.x;
    const int w = tid >> 6, lane = tid & 63;
    const int l15 = lane & 15, g = lane >> 4;
    const int wr = w >> 1, wc = w & 1;
    const int n0 = blockIdx.y * 128;
    const int j0 = blockIdx.x * 128;

    f32x4 acc[4][4];
#pragma unroll
    for (int mi = 0; mi < 4; mi++)
#pragma unroll
        for (int nj = 0; nj < 4; nj++) acc[mi][nj] = (f32x4){0.f, 0.f, 0.f, 0.f};

    // per-thread staging chunk geometry: chunk ci covers (row ci>>3, 16B pos ci&7)
    u32x4 pa[4], pb[4];
#define LOADREGS(KS)                                                          \
    {                                                                         \
        _Pragma("unroll")                                                     \
        for (int it = 0; it < 4; it++) {                                      \
            int ci = tid + it * 256;                                          \
            int r = ci >> 3, p = ci & 7;                                      \
            pa[it] = *(const u32x4*)(A + (size_t)(n0 + r) * K + (KS) + p * 8);\
            pb[it] = *(const u32x4*)(W + (size_t)(j0 + r) * K + (KS) + p * 8);\
        }                                                                     \
    }

    LOADREGS(0)

    for (int ks = 0; ks < K; ks += 64) {
        __syncthreads();
#pragma unroll
        for (int it = 0; it < 4; it++) {
            int ci = tid + it * 256;
            int r = ci >> 3, p = ci & 7;
            int d = r * 64 + ((p ^ (r & 7)) << 3);
            *(u32x4*)(As + d) = pa[it];
            *(u32x4*)(Ws + d) = pb[it];
        }
        __syncthreads();
        if (ks + 64 < K) LOADREGS(ks + 64)

#pragma unroll
        for (int c = 0; c < 2; c++) {
            f16x8 af[4], bf[4];
            const int q0c = c * 4 + (g >> 1);       // chunk of k=c*32+4g
            const int q1c = q0c + 2;                // chunk of k=c*32+16+4g
            const int off = (g & 1) << 2;           // 8B half of the chunk
#pragma unroll
            for (int mi = 0; mi < 4; mi++) {
                int r = wr * 64 + mi * 16 + l15;
                int sw = r & 7;
                const unsigned short* rp = As + r * 64;
                u32x2 x0 = *(const u32x2*)(rp + ((q0c ^ sw) << 3) + off);
                u32x2 x1 = *(const u32x2*)(rp + ((q1c ^ sw) << 3) + off);
                u32x4 uu = {x0.x, x0.y, x1.x, x1.y};
                af[mi] = __builtin_bit_cast(f16x8, uu);
            }
#pragma unroll
            for (int nj = 0; nj < 4; nj++) {
                int r = wc * 64 + nj * 16 + l15;
                int sw = r & 7;
                const unsigned short* rp = Ws + r * 64;
                u32x2 x0 = *(const u32x2*)(rp + ((q0c ^ sw) << 3) + off);
                u32x2 x1 = *(const u32x2*)(rp + ((q1c ^ sw) << 3) + off);
                u32x4 uu = {x0.x, x0.y, x1.x, x1.y};
                bf[nj] = __builtin_bit_cast(f16x8, uu);
            }
#pragma unroll
            for (int mi = 0; mi < 4; mi++)
#pragma unroll
                for (int nj = 0; nj < 4; nj++)
                    acc[mi][nj] = __builtin_amdgcn_mfma_f32_16x16x32_f16(
                        af[mi], bf[nj], acc[mi][nj], 0, 0, 0);
        }
    }
#undef LOADREGS

    // epilogue: D[row=4g+r][col=l15] per frag; n from A-side, j from W-side
#pragma unroll
    for (int nj = 0; nj < 4; nj++) {
        int j = j0 + wc * 64 + nj * 16 + l15;
        float bb = bias[j];
#pragma unroll
        for (int mi = 0; mi < 4; mi++) {
#pragma unroll
            for (int r = 0; r < 4; r++) {
                int n = n0 + wr * 64 + mi * 16 + 4 * g + r;
                float vv = acc[mi][nj][r] + bb;
                if (mode == 0) {
                    ((float*)outp)[(size_t)n * J + j] = vv;
                } else {
                    int b = n >> 11, t = n & (TT - 1);
                    int h = j >> 6, dd = j & 63;
                    ((unsigned short*)outp)[(((size_t)(b * HH + h) * TT + t) << 6) + dd] = f2h(vv);
                }
            }
        }
    }
}

// ---------------------------------------------------------------------------
// RoPE (rotate-half) in-place on [B,H,T,64] f16.
// ---------------------------------------------------------------------------
__global__ __launch_bounds__(256) void rope_kernel(unsigned short* __restrict__ buf)
{
    int idx = blockIdx.x * 256 + threadIdx.x;    // B*H*T*32 total
    int i = idx & 31;
    int t = (idx >> 5) & (TT - 1);
    int bh = idx >> 16;
    size_t base = ((size_t)bh * TT + t) * 64;
    float x1 = h2f(buf[base + i]);
    float x2 = h2f(buf[base + 32 + i]);
    float theta = exp2f(-(float)i * (13.287712379549449f / 32.0f));
    float ang = (float)(t + 1) * theta;
    float s = sinf(ang), c = cosf(ang);
    buf[base + i]       = f2h(x1 * c - x2 * s);
    buf[base + 32 + i]  = f2h(x2 * c + x1 * s);
}

// ---------------------------------------------------------------------------
// MFMA flash attention (f16). Structure identical to verified R1 kernel;
// only dtype changed (bf16 -> f16) and output is f16 [B,T,D] (attn scratch).
// ---------------------------------------------------------------------------
__device__ __forceinline__ u32x2 ds_tr16(const unsigned short* p) {
    u32x2 r;
    asm volatile("ds_read_b64_tr_b16 %0, %1"
                 : "=v"(r)
                 : "v"((unsigned int)(unsigned long long)p));
    return r;
}

__global__ __launch_bounds__(256) void attn_mfma(
    const unsigned short* __restrict__ q,
    const unsigned short* __restrict__ k,
    const unsigned short* __restrict__ v,
    unsigned short* __restrict__ aout)
{
    __shared__ __align__(16) unsigned short Ks[64 * 64];   // swizzled [key][dim]
    __shared__ __align__(16) unsigned short Vs[4 * 1056];  // [db][key][16]

    const int qt = blockIdx.x, h = blockIdx.y, b = blockIdx.z;
    const int tid = threadIdx.x;
    const int w = tid >> 6;
    const int lane = tid & 63;
    const int l15 = lane & 15, g = lane >> 4;
    const int bh = b * HH + h;
    const size_t base = (size_t)bh * TT * 64;
    const unsigned short* Qp = q + base;
    const unsigned short* Kp = k + base;
    const unsigned short* Vp = v + base;
    const int q0 = qt * 64;

    f16x8 qf[2];
    {
        const unsigned short* Qr = Qp + (size_t)(q0 + w * 16 + l15) * 64;
#pragma unroll
        for (int c = 0; c < 2; c++) {
            u32x2 a0 = *(const u32x2*)(Qr + 32 * c + 4 * g);
            u32x2 a1 = *(const u32x2*)(Qr + 32 * c + 16 + 4 * g);
            u32x4 uu = {a0.x, a0.y, a1.x, a1.y};
            qf[c] = __builtin_bit_cast(f16x8, uu);
        }
    }

    float mrow = -1e30f, lrow = 0.f;
    f32x4 accO[4];
#pragma unroll
    for (int nb = 0; nb < 4; nb++) accO[nb] = (f32x4){0.f, 0.f, 0.f, 0.f};

    const float SC = 0.18033688011112042f;   // log2(e)/8

    const int ntiles = qt + 1;
    for (int kt = 0; kt < ntiles; kt++) {
        const int kbase = kt * 64;
        const bool diag = (kt == qt);
        __syncthreads();
#pragma unroll
        for (int it = 0; it < 2; it++) {
            int vi = tid + it * 256;
            int key = vi >> 3, pr = vi & 7;
            u32x4 val = *(const u32x4*)(Kp + (size_t)(kbase + key) * 64 + pr * 8);
            *(u32x4*)(Ks + key * 64 + ((pr ^ (key & 7)) << 3)) = val;
        }
#pragma unroll
        for (int it = 0; it < 4; it++) {
            int vi = tid + it * 256;
            int key = vi >> 4, c4 = vi & 15;
            u32x2 val = *(const u32x2*)(Vp + (size_t)(kbase + key) * 64 + c4 * 4);
            *(u32x2*)(Vs + (c4 >> 2) * 1056 + key * 16 + (c4 & 3) * 4) = val;
        }
        __syncthreads();

        const int nkb = diag ? (w + 1) : 4;
        f32x4 accS[4];
#pragma unroll
        for (int kb = 0; kb < 4; kb++) accS[kb] = (f32x4){0.f, 0.f, 0.f, 0.f};
#pragma unroll
        for (int kb = 0; kb < 4; kb++) {
            if (kb < nkb) {
                int key = kb * 16 + l15;
                int sw = key & 7;
#pragma unroll
                for (int c = 0; c < 2; c++) {
                    int c8a = 8 * c + g, c8b = 8 * c + 4 + g;
                    u32x2 x0 = *(const u32x2*)(Ks + key * 64 +
                                   (((c8a >> 1) ^ sw) << 3) + ((c8a & 1) << 2));
                    u32x2 x1 = *(const u32x2*)(Ks + key * 64 +
                                   (((c8b >> 1) ^ sw) << 3) + ((c8b & 1) << 2));
                    u32x4 uu = {x0.x, x0.y, x1.x, x1.y};
                    accS[kb] = __builtin_amdgcn_mfma_f32_16x16x32_f16(
                        __builtin_bit_cast(f16x8, uu), qf[c], accS[kb], 0, 0, 0);
                }
            }
        }

        float sloc[16];
        float tmax = -1e30f;
#pragma unroll
        for (int kb = 0; kb < 4; kb++)
#pragma unroll
            for (int r = 0; r < 4; r++) {
                float s = accS[kb][r];
                bool valid = !diag || (kb * 16 + 4 * g + r <= w * 16 + l15);
                s = valid ? s : -1e30f;
                sloc[kb * 4 + r] = s;
                tmax = fmaxf(tmax, s);
            }
        tmax = fmaxf(tmax, __shfl_xor(tmax, 16));
        tmax = fmaxf(tmax, __shfl_xor(tmax, 32));

        float mnew = fmaxf(mrow, tmax);
        float sf = exp2f((mrow - mnew) * SC);
        mrow = mnew;

        unsigned int pw[8];
        float psum = 0.f;
#pragma unroll
        for (int i = 0; i < 8; i++) {
            float p0 = exp2f((sloc[2 * i]     - mnew) * SC);
            float p1 = exp2f((sloc[2 * i + 1] - mnew) * SC);
            unsigned short h0 = f2h(p0), h1 = f2h(p1);
            pw[i] = (unsigned int)h0 | ((unsigned int)h1 << 16);
            psum += h2f(h0) + h2f(h1);
        }
        psum += __shfl_xor(psum, 16);
        psum += __shfl_xor(psum, 32);
        lrow = lrow * sf + psum;

        float sfr[4];
#pragma unroll
        for (int r = 0; r < 4; r++) sfr[r] = __shfl(sf, 4 * g + r);
#pragma unroll
        for (int nb = 0; nb < 4; nb++)
#pragma unroll
            for (int r = 0; r < 4; r++) accO[nb][r] *= sfr[r];

        const int nkc = (diag && w < 2) ? 1 : 2;
        u32x2 vfr[2][4][2];
#pragma unroll
        for (int kc = 0; kc < 2; kc++)
            if (kc < nkc)
#pragma unroll
                for (int nb = 0; nb < 4; nb++)
#pragma unroll
                    for (int t2 = 0; t2 < 2; t2++)
                        vfr[kc][nb][t2] = ds_tr16(
                            Vs + nb * 1056 + (kc * 32 + 16 * t2) * 16 + 4 * lane);
        asm volatile("s_waitcnt lgkmcnt(0)" ::: "memory");
        __builtin_amdgcn_sched_barrier(0);

#pragma unroll
        for (int kc = 0; kc < 2; kc++)
            if (kc < nkc) {
                u32x4 pu = {pw[4 * kc + 0], pw[4 * kc + 1], pw[4 * kc + 2], pw[4 * kc + 3]};
                f16x8 pf = __builtin_bit_cast(f16x8, pu);
#pragma unroll
                for (int nb = 0; nb < 4; nb++) {
                    u32x4 vu = {vfr[kc][nb][0].x, vfr[kc][nb][0].y,
                                vfr[kc][nb][1].x, vfr[kc][nb][1].y};
                    accO[nb] = __builtin_amdgcn_mfma_f32_16x16x32_f16(
                        pf, __builtin_bit_cast(f16x8, vu), accO[nb], 0, 0, 0);
                }
            }
    }

    // epilogue: O /= l ; write f16 [B,T,D] (attn scratch for O-proj)
    float linv = 1.0f / lrow;
    float sfr[4];
#pragma unroll
    for (int r = 0; r < 4; r++) sfr[r] = __shfl(linv, 4 * g + r);
#pragma unroll
    for (int r = 0; r < 4; r++) {
        int qr = q0 + w * 16 + 4 * g + r;
        unsigned short* orow = aout + (size_t)(b * TT + qr) * DD + h * 64;
#pragma unroll
        for (int nb = 0; nb < 4; nb++)
            orow[nb * 16 + l15] = f2h(accO[nb][r] * sfr[r]);
    }
}

// ---------------------------------------------------------------------------
extern "C" void kernel_launch(void* const* d_in, const int* in_sizes, int n_in,
                              void* d_out, int out_size, void* d_ws, size_t ws_size,
                              hipStream_t stream)
{
    const float* x  = (const float*)d_in[0];
    const float* Wq = (const float*)d_in[1];
    const float* bq = (const float*)d_in[2];
    const float* Wk = (const float*)d_in[3];
    const float* bk = (const float*)d_in[4];
    const float* Wv = (const float*)d_in[5];
    const float* bv = (const float*)d_in[6];
    const float* Wo = (const float*)d_in[7];
    const float* bo = (const float*)d_in[8];
    float* out = (float*)d_out;                     // FLOAT32 output [B,T,D]

    const size_t NE = (size_t)BB * HH * TT * HD;    // 8388608 elements
    // ws (50.3 MB, same budget as verified R1): q/k/v f16.
    unsigned short* qb   = (unsigned short*)d_ws;
    unsigned short* kbuf = qb + NE;
    unsigned short* vbuf = kbuf + NE;
    float* res = (float*)d_ws;                      // overlays dead q+k after attn

    // d_out (33.5 MB f32) used as scratch before the final result lands:
    //  [0 .. 16.78M)   x_h f16  (later overwritten by att_h f16, same extent)
    //  [16.78M .. 25.2M) Wq_h, Wk_h, Wv_h, Wo_h f16 (2 MB each)
    unsigned short* ds  = (unsigned short*)d_out;
    unsigned short* xh  = ds;                       // 8388608 f16
    unsigned short* wqh = ds + 8388608;
    unsigned short* wkh = wqh + 1048576;
    unsigned short* wvh = wkh + 1048576;
    unsigned short* woh = wvh + 1048576;
    unsigned short* att = ds;                       // att_h overlays dead x_h

    const int N = BB * TT;                          // 8192 tokens
    dim3 blk(256);
    dim3 gp(DD / 128, N / 128);                     // (8, 64)

    conv_h<<<8192, blk, 0, stream>>>(x,  xh,  2097152);
    conv_h<<<1024, blk, 0, stream>>>(Wq, wqh, 262144);
    conv_h<<<1024, blk, 0, stream>>>(Wk, wkh, 262144);
    conv_h<<<1024, blk, 0, stream>>>(Wv, wvh, 262144);
    conv_h<<<1024, blk, 0, stream>>>(Wo, woh, 262144);

    gemm_h<<<gp, blk, 0, stream>>>(xh, wqh, bq, qb,   N, DD, DD, 1);
    gemm_h<<<gp, blk, 0, stream>>>(xh, wkh, bk, kbuf, N, DD, DD, 1);
    gemm_h<<<gp, blk, 0, stream>>>(xh, wvh, bv, vbuf, N, DD, DD, 1);

    int rope_total = BB * HH * TT * 32;             // 4194304
    rope_kernel<<<rope_total / 256, 256, 0, stream>>>(qb);
    rope_kernel<<<rope_total / 256, 256, 0, stream>>>(kbuf);

    // flash attention -> f16 att scratch (d_out low region; x_h is dead)
    attn_mfma<<<dim3(TT / 64, HH, BB), blk, 0, stream>>>(qb, kbuf, vbuf, att);

    // O-projection: A = att (f16), W = Wo_h -> f32 res (dead q+k ws region)
    gemm_h<<<gp, blk, 0, stream>>>(att, woh, bo, res, N, DD, DD, 0);

    // final result -> d_out
    hipMemcpyAsync(out, res, (size_t)N * DD * sizeof(float),
                   hipMemcpyDeviceToDevice, stream);
}

// Round 4
// 367.351 us; speedup vs baseline: 30.8795x; 1.3439x over previous
//
#include <hip/hip_runtime.h>

// Problem constants: B=4, T=2048, D=1024, H=16, HD=64
// Math (certified r6): torch convention x@W.T+b, rotate-half RoPE pos=t+1,
// causal softmax(QK^T/8)V, O-proj. Output f32 [B,T,D].
// R4 = R3 with cvt_pkrtz return-type fix (__fp16 vector, bit-cast to u32).
// R3: attn load-balance (q-tile pairing i & 31-i -> uniform 33 tiles/block,
// 1024 blocks = 4/CU), reg-staged K/V prefetch, softmax VALU diet
// (cvt_pkrtz, f32 psum, defer-max THR=11 log2, setprio around MFMA).
#define BB 4
#define TT 2048
#define DD 1024
#define HH 16
#define HD 64

typedef __attribute__((ext_vector_type(8))) _Float16 f16x8;
typedef __attribute__((ext_vector_type(4))) float f32x4;
typedef __attribute__((ext_vector_type(2))) unsigned int u32x2;
typedef __attribute__((ext_vector_type(4))) unsigned int u32x4;

__device__ __forceinline__ float h2f(unsigned short u) {
    return (float)__builtin_bit_cast(_Float16, u);
}
__device__ __forceinline__ unsigned short f2h(float f) {
    return __builtin_bit_cast(unsigned short, (_Float16)f);
}
__device__ __forceinline__ unsigned int pkrtz(float a, float b) {
    return __builtin_bit_cast(unsigned int, __builtin_amdgcn_cvt_pkrtz(a, b));
}

// ---------------------------------------------------------------------------
// f32 -> f16 convert (vectorized, exact grid)
// ---------------------------------------------------------------------------
__global__ __launch_bounds__(256) void conv_h(
    const float* __restrict__ in, unsigned short* __restrict__ out, int n4)
{
    int i = blockIdx.x * 256 + threadIdx.x;
    if (i < n4) {
        float4 v = ((const float4*)in)[i];
        ushort4 o = { f2h(v.x), f2h(v.y), f2h(v.z), f2h(v.w) };
        ((ushort4*)out)[i] = o;
    }
}

// ---------------------------------------------------------------------------
// MFMA f16 GEMM (torch convention): out[n,j] = sum_k A[n,k]*W[j,k] + bias[j]
// (verified R2 structure, unchanged)
// ---------------------------------------------------------------------------
__global__ __launch_bounds__(256) void gemm_h(
    const unsigned short* __restrict__ A, const unsigned short* __restrict__ W,
    const float* __restrict__ bias, void* __restrict__ outp,
    int N, int K, int J, int mode)
{
    __shared__ __align__(16) unsigned short As[128 * 64];
    __shared__ __align__(16) unsigned short Ws[128 * 64];

    const int tid = threadIdx.x;
    const int w = tid >> 6, lane = tid & 63;
    const int l15 = lane & 15, g = lane >> 4;
    const int wr = w >> 1, wc = w & 1;
    const int n0 = blockIdx.y * 128;
    const int j0 = blockIdx.x * 128;

    f32x4 acc[4][4];
#pragma unroll
    for (int mi = 0; mi < 4; mi++)
#pragma unroll
        for (int nj = 0; nj < 4; nj++) acc[mi][nj] = (f32x4){0.f, 0.f, 0.f, 0.f};

    u32x4 pa[4], pb[4];
#define LOADREGS(KS)                                                          \
    {                                                                         \
        _Pragma("unroll")                                                     \
        for (int it = 0; it < 4; it++) {                                      \
            int ci = tid + it * 256;                                          \
            int r = ci >> 3, p = ci & 7;                                      \
            pa[it] = *(const u32x4*)(A + (size_t)(n0 + r) * K + (KS) + p * 8);\
            pb[it] = *(const u32x4*)(W + (size_t)(j0 + r) * K + (KS) + p * 8);\
        }                                                                     \
    }

    LOADREGS(0)

    for (int ks = 0; ks < K; ks += 64) {
        __syncthreads();
#pragma unroll
        for (int it = 0; it < 4; it++) {
            int ci = tid + it * 256;
            int r = ci >> 3, p = ci & 7;
            int d = r * 64 + ((p ^ (r & 7)) << 3);
            *(u32x4*)(As + d) = pa[it];
            *(u32x4*)(Ws + d) = pb[it];
        }
        __syncthreads();
        if (ks + 64 < K) LOADREGS(ks + 64)

#pragma unroll
        for (int c = 0; c < 2; c++) {
            f16x8 af[4], bf[4];
            const int q0c = c * 4 + (g >> 1);
            const int q1c = q0c + 2;
            const int off = (g & 1) << 2;
#pragma unroll
            for (int mi = 0; mi < 4; mi++) {
                int r = wr * 64 + mi * 16 + l15;
                int sw = r & 7;
                const unsigned short* rp = As + r * 64;
                u32x2 x0 = *(const u32x2*)(rp + ((q0c ^ sw) << 3) + off);
                u32x2 x1 = *(const u32x2*)(rp + ((q1c ^ sw) << 3) + off);
                u32x4 uu = {x0.x, x0.y, x1.x, x1.y};
                af[mi] = __builtin_bit_cast(f16x8, uu);
            }
#pragma unroll
            for (int nj = 0; nj < 4; nj++) {
                int r = wc * 64 + nj * 16 + l15;
                int sw = r & 7;
                const unsigned short* rp = Ws + r * 64;
                u32x2 x0 = *(const u32x2*)(rp + ((q0c ^ sw) << 3) + off);
                u32x2 x1 = *(const u32x2*)(rp + ((q1c ^ sw) << 3) + off);
                u32x4 uu = {x0.x, x0.y, x1.x, x1.y};
                bf[nj] = __builtin_bit_cast(f16x8, uu);
            }
#pragma unroll
            for (int mi = 0; mi < 4; mi++)
#pragma unroll
                for (int nj = 0; nj < 4; nj++)
                    acc[mi][nj] = __builtin_amdgcn_mfma_f32_16x16x32_f16(
                        af[mi], bf[nj], acc[mi][nj], 0, 0, 0);
        }
    }
#undef LOADREGS

#pragma unroll
    for (int nj = 0; nj < 4; nj++) {
        int j = j0 + wc * 64 + nj * 16 + l15;
        float bb = bias[j];
#pragma unroll
        for (int mi = 0; mi < 4; mi++) {
#pragma unroll
            for (int r = 0; r < 4; r++) {
                int n = n0 + wr * 64 + mi * 16 + 4 * g + r;
                float vv = acc[mi][nj][r] + bb;
                if (mode == 0) {
                    ((float*)outp)[(size_t)n * J + j] = vv;
                } else {
                    int b = n >> 11, t = n & (TT - 1);
                    int h = j >> 6, dd = j & 63;
                    ((unsigned short*)outp)[(((size_t)(b * HH + h) * TT + t) << 6) + dd] = f2h(vv);
                }
            }
        }
    }
}

// ---------------------------------------------------------------------------
// RoPE (rotate-half) in-place on [B,H,T,64] f16.
// ---------------------------------------------------------------------------
__global__ __launch_bounds__(256) void rope_kernel(unsigned short* __restrict__ buf)
{
    int idx = blockIdx.x * 256 + threadIdx.x;    // B*H*T*32 total
    int i = idx & 31;
    int t = (idx >> 5) & (TT - 1);
    int bh = idx >> 16;
    size_t base = ((size_t)bh * TT + t) * 64;
    float x1 = h2f(buf[base + i]);
    float x2 = h2f(buf[base + 32 + i]);
    float theta = exp2f(-(float)i * (13.287712379549449f / 32.0f));
    float ang = (float)(t + 1) * theta;
    float s = sinf(ang), c = cosf(ang);
    buf[base + i]       = f2h(x1 * c - x2 * s);
    buf[base + 32 + i]  = f2h(x2 * c + x1 * s);
}

// ---------------------------------------------------------------------------
// MFMA flash attention (f16), R3 structure.
// Grid (T/128, H, B) = (16,16,4); block = 4 waves; each block processes
// q-tile pair (i, 31-i) -> uniform 33 KV-tile iterations per block.
// ---------------------------------------------------------------------------
__device__ __forceinline__ u32x2 ds_tr16(const unsigned short* p) {
    u32x2 r;
    asm volatile("ds_read_b64_tr_b16 %0, %1"
                 : "=v"(r)
                 : "v"((unsigned int)(unsigned long long)p));
    return r;
}

__global__ __launch_bounds__(256, 4) void attn_mfma(
    const unsigned short* __restrict__ q,
    const unsigned short* __restrict__ k,
    const unsigned short* __restrict__ v,
    unsigned short* __restrict__ aout)
{
    __shared__ __align__(16) unsigned short Ks[64 * 64];   // swizzled [key][dim]
    __shared__ __align__(16) unsigned short Vs[4 * 1056];  // [db][key][16]

    const int h = blockIdx.y, b = blockIdx.z;
    const int tid = threadIdx.x;
    const int w = tid >> 6;
    const int lane = tid & 63;
    const int l15 = lane & 15, g = lane >> 4;
    const int bh = b * HH + h;
    const size_t base = (size_t)bh * TT * 64;
    const unsigned short* Qp = q + base;
    const unsigned short* Kp = k + base;
    const unsigned short* Vp = v + base;

    const float SC = 0.18033688011112042f;   // log2(e)/8

    u32x4 kreg[2];
    u32x2 vreg[4];
#define LOADKV(KB)                                                             \
    {                                                                          \
        _Pragma("unroll")                                                      \
        for (int it = 0; it < 2; it++) {                                       \
            int vi = tid + it * 256;                                           \
            int key = vi >> 3, pr = vi & 7;                                    \
            kreg[it] = *(const u32x4*)(Kp + (size_t)((KB) + key) * 64 + pr * 8);\
        }                                                                      \
        _Pragma("unroll")                                                      \
        for (int it = 0; it < 4; it++) {                                       \
            int vi = tid + it * 256;                                           \
            int key = vi >> 4, c4 = vi & 15;                                   \
            vreg[it] = *(const u32x2*)(Vp + (size_t)((KB) + key) * 64 + c4 * 4);\
        }                                                                      \
    }

    for (int ph = 0; ph < 2; ph++) {
        const int qt = ph ? (31 - (int)blockIdx.x) : (int)blockIdx.x;
        const int q0 = qt * 64;

        // Q fragments for this phase
        f16x8 qf[2];
        {
            const unsigned short* Qr = Qp + (size_t)(q0 + w * 16 + l15) * 64;
#pragma unroll
            for (int c = 0; c < 2; c++) {
                u32x2 a0 = *(const u32x2*)(Qr + 32 * c + 4 * g);
                u32x2 a1 = *(const u32x2*)(Qr + 32 * c + 16 + 4 * g);
                u32x4 uu = {a0.x, a0.y, a1.x, a1.y};
                qf[c] = __builtin_bit_cast(f16x8, uu);
            }
        }

        float mrow = -1e30f, lrow = 0.f;
        f32x4 accO[4];
#pragma unroll
        for (int nb = 0; nb < 4; nb++) accO[nb] = (f32x4){0.f, 0.f, 0.f, 0.f};

        const int ntiles = qt + 1;
        LOADKV(0)

        for (int kt = 0; kt < ntiles; kt++) {
            const bool diag = (kt == qt);
            __syncthreads();
            // ---- write staged regs -> LDS (K swizzled, V subtiled)
#pragma unroll
            for (int it = 0; it < 2; it++) {
                int vi = tid + it * 256;
                int key = vi >> 3, pr = vi & 7;
                *(u32x4*)(Ks + key * 64 + ((pr ^ (key & 7)) << 3)) = kreg[it];
            }
#pragma unroll
            for (int it = 0; it < 4; it++) {
                int vi = tid + it * 256;
                int key = vi >> 4, c4 = vi & 15;
                *(u32x2*)(Vs + (c4 >> 2) * 1056 + key * 16 + (c4 & 3) * 4) = vreg[it];
            }
            __syncthreads();
            if (kt + 1 < ntiles) LOADKV((kt + 1) * 64)

            // ---- S^T = K * Q^T
            const int nkb = diag ? (w + 1) : 4;
            f32x4 accS[4];
#pragma unroll
            for (int kb = 0; kb < 4; kb++) accS[kb] = (f32x4){0.f, 0.f, 0.f, 0.f};
            __builtin_amdgcn_s_setprio(1);
#pragma unroll
            for (int kb = 0; kb < 4; kb++) {
                if (kb < nkb) {
                    int key = kb * 16 + l15;
                    int sw = key & 7;
#pragma unroll
                    for (int c = 0; c < 2; c++) {
                        int c8a = 8 * c + g, c8b = 8 * c + 4 + g;
                        u32x2 x0 = *(const u32x2*)(Ks + key * 64 +
                                       (((c8a >> 1) ^ sw) << 3) + ((c8a & 1) << 2));
                        u32x2 x1 = *(const u32x2*)(Ks + key * 64 +
                                       (((c8b >> 1) ^ sw) << 3) + ((c8b & 1) << 2));
                        u32x4 uu = {x0.x, x0.y, x1.x, x1.y};
                        accS[kb] = __builtin_amdgcn_mfma_f32_16x16x32_f16(
                            __builtin_bit_cast(f16x8, uu), qf[c], accS[kb], 0, 0, 0);
                    }
                }
            }
            __builtin_amdgcn_s_setprio(0);

            // ---- mask (diag) + per-row max
            float sloc[16];
            float tmax = -1e30f;
            if (diag) {
#pragma unroll
                for (int kb = 0; kb < 4; kb++)
#pragma unroll
                    for (int r = 0; r < 4; r++) {
                        float s = accS[kb][r];
                        bool valid = (kb * 16 + 4 * g + r <= w * 16 + l15);
                        s = valid ? s : -1e30f;
                        sloc[kb * 4 + r] = s;
                        tmax = fmaxf(tmax, s);
                    }
            } else {
#pragma unroll
                for (int kb = 0; kb < 4; kb++)
#pragma unroll
                    for (int r = 0; r < 4; r++) {
                        float s = accS[kb][r];
                        sloc[kb * 4 + r] = s;
                        tmax = fmaxf(tmax, s);
                    }
            }
            tmax = fmaxf(tmax, __shfl_xor(tmax, 16));
            tmax = fmaxf(tmax, __shfl_xor(tmax, 32));

            // ---- defer-max: rescale only when headroom (2^11) exceeded
            if (!__all(tmax - mrow <= 61.0f)) {     // 61*SC = 11 log2-units
                float mnew = fmaxf(mrow, tmax);
                float sf = exp2f((mrow - mnew) * SC);
                mrow = mnew;
                lrow *= sf;
                float sfr[4];
#pragma unroll
                for (int r = 0; r < 4; r++) sfr[r] = __shfl(sf, 4 * g + r);
#pragma unroll
                for (int nb = 0; nb < 4; nb++)
#pragma unroll
                    for (int r = 0; r < 4; r++) accO[nb][r] *= sfr[r];
            }

            // ---- P = exp2(fma(s,SC,-m*SC)), packed RTZ; psum in f32
            const float nmsc = -mrow * SC;
            unsigned int pw[8];
            float psum = 0.f;
#pragma unroll
            for (int i = 0; i < 8; i++) {
                float p0 = exp2f(fmaf(sloc[2 * i],     SC, nmsc));
                float p1 = exp2f(fmaf(sloc[2 * i + 1], SC, nmsc));
                pw[i] = pkrtz(p0, p1);
                psum += p0 + p1;
            }
            psum += __shfl_xor(psum, 16);
            psum += __shfl_xor(psum, 32);
            lrow += psum;

            // ---- PV: V frags via tr-read (per-kc batch), P from pw
            const int nkc = (diag && w < 2) ? 1 : 2;
#pragma unroll
            for (int kc = 0; kc < 2; kc++)
                if (kc < nkc) {
                    u32x2 vfr[4][2];
#pragma unroll
                    for (int nb = 0; nb < 4; nb++)
#pragma unroll
                        for (int t2 = 0; t2 < 2; t2++)
                            vfr[nb][t2] = ds_tr16(
                                Vs + nb * 1056 + (kc * 32 + 16 * t2) * 16 + 4 * lane);
                    asm volatile("s_waitcnt lgkmcnt(0)" ::: "memory");
                    __builtin_amdgcn_sched_barrier(0);
                    u32x4 pu = {pw[4 * kc + 0], pw[4 * kc + 1], pw[4 * kc + 2], pw[4 * kc + 3]};
                    f16x8 pf = __builtin_bit_cast(f16x8, pu);
                    __builtin_amdgcn_s_setprio(1);
#pragma unroll
                    for (int nb = 0; nb < 4; nb++) {
                        u32x4 vu = {vfr[nb][0].x, vfr[nb][0].y,
                                    vfr[nb][1].x, vfr[nb][1].y};
                        accO[nb] = __builtin_amdgcn_mfma_f32_16x16x32_f16(
                            pf, __builtin_bit_cast(f16x8, vu), accO[nb], 0, 0, 0);
                    }
                    __builtin_amdgcn_s_setprio(0);
                }
        }

        // ---- epilogue: O /= l ; write f16 [B,T,D]
        float linv = 1.0f / lrow;
        float sfr[4];
#pragma unroll
        for (int r = 0; r < 4; r++) sfr[r] = __shfl(linv, 4 * g + r);
#pragma unroll
        for (int r = 0; r < 4; r++) {
            int qr = q0 + w * 16 + 4 * g + r;
            unsigned short* orow = aout + (size_t)(b * TT + qr) * DD + h * 64;
#pragma unroll
            for (int nb = 0; nb < 4; nb++)
                orow[nb * 16 + l15] = f2h(accO[nb][r] * sfr[r]);
        }
    }
#undef LOADKV
}

// ---------------------------------------------------------------------------
extern "C" void kernel_launch(void* const* d_in, const int* in_sizes, int n_in,
                              void* d_out, int out_size, void* d_ws, size_t ws_size,
                              hipStream_t stream)
{
    const float* x  = (const float*)d_in[0];
    const float* Wq = (const float*)d_in[1];
    const float* bq = (const float*)d_in[2];
    const float* Wk = (const float*)d_in[3];
    const float* bk = (const float*)d_in[4];
    const float* Wv = (const float*)d_in[5];
    const float* bv = (const float*)d_in[6];
    const float* Wo = (const float*)d_in[7];
    const float* bo = (const float*)d_in[8];
    float* out = (float*)d_out;                     // FLOAT32 output [B,T,D]

    const size_t NE = (size_t)BB * HH * TT * HD;    // 8388608 elements
    // ws (50.3 MB): q/k/v f16.
    unsigned short* qb   = (unsigned short*)d_ws;
    unsigned short* kbuf = qb + NE;
    unsigned short* vbuf = kbuf + NE;
    float* res = (float*)d_ws;                      // overlays dead q+k after attn

    // d_out scratch layout (all dead before final result lands):
    //  [0 .. 16.78M)   x_h f16  (later overwritten by att_h f16)
    //  [16.78M ..)     Wq_h, Wk_h, Wv_h, Wo_h f16 (2 MB each)
    unsigned short* ds  = (unsigned short*)d_out;
    unsigned short* xh  = ds;
    unsigned short* wqh = ds + 8388608;
    unsigned short* wkh = wqh + 1048576;
    unsigned short* wvh = wkh + 1048576;
    unsigned short* woh = wvh + 1048576;
    unsigned short* att = ds;                       // att_h overlays dead x_h

    const int N = BB * TT;                          // 8192 tokens
    dim3 blk(256);
    dim3 gp(DD / 128, N / 128);                     // (8, 64)

    conv_h<<<8192, blk, 0, stream>>>(x,  xh,  2097152);
    conv_h<<<1024, blk, 0, stream>>>(Wq, wqh, 262144);
    conv_h<<<1024, blk, 0, stream>>>(Wk, wkh, 262144);
    conv_h<<<1024, blk, 0, stream>>>(Wv, wvh, 262144);
    conv_h<<<1024, blk, 0, stream>>>(Wo, woh, 262144);

    gemm_h<<<gp, blk, 0, stream>>>(xh, wqh, bq, qb,   N, DD, DD, 1);
    gemm_h<<<gp, blk, 0, stream>>>(xh, wkh, bk, kbuf, N, DD, DD, 1);
    gemm_h<<<gp, blk, 0, stream>>>(xh, wvh, bv, vbuf, N, DD, DD, 1);

    int rope_total = BB * HH * TT * 32;             // 4194304
    rope_kernel<<<rope_total / 256, 256, 0, stream>>>(qb);
    rope_kernel<<<rope_total / 256, 256, 0, stream>>>(kbuf);

    // flash attention (paired q-tiles) -> f16 att scratch in d_out
    attn_mfma<<<dim3(TT / 128, HH, BB), blk, 0, stream>>>(qb, kbuf, vbuf, att);

    // O-projection: A = att (f16), W = Wo_h -> f32 res (dead q+k ws region)
    gemm_h<<<gp, blk, 0, stream>>>(att, woh, bo, res, N, DD, DD, 0);

    // final result -> d_out
    hipMemcpyAsync(out, res, (size_t)N * DD * sizeof(float),
                   hipMemcpyDeviceToDevice, stream);
}